// Round 2
// baseline (1166.655 us; speedup 1.0000x reference)
//
#include <hip/hip_runtime.h>
#include <math.h>

#define BB 128
#define PP 34125
#define OO 16
#define CC 21
#define HBINS 8192
#define HSHIFT 18
#define CAND_MAX 2048
#define VAR0f 0.1f
#define VAR1f 0.2f
#define THRESHf 0.35f

// ---------------- Phase A: best prior per truth (argmax over P), 8 blocks/row ----------------
__global__ __launch_bounds__(256) void mb_phaseA(const float* __restrict__ priors,
                                                 const float* __restrict__ targets,
                                                 unsigned long long* __restrict__ keys) {
    int b = blockIdx.y, tid = threadIdx.x;
    __shared__ float tr[OO][4];
    __shared__ unsigned long long skeys[OO];
    if (tid < OO * 5) {
        int o = tid / 5, c = tid % 5;
        float v = targets[((size_t)b * OO + o) * 5 + c];
        if (c < 4) tr[o][c] = v;
    }
    if (tid < OO) skeys[tid] = 0ull;
    __syncthreads();

    unsigned long long best[OO];
#pragma unroll
    for (int o = 0; o < OO; o++) best[o] = 0ull;

    for (int p = blockIdx.x * 256 + tid; p < PP; p += gridDim.x * 256) {
        float4 pr = ((const float4*)priors)[p];
        float bx0 = pr.x - pr.z * 0.5f, by0 = pr.y - pr.w * 0.5f;
        float bx1 = pr.x + pr.z * 0.5f, by1 = pr.y + pr.w * 0.5f;
        float area_b = (bx1 - bx0) * (by1 - by0);
#pragma unroll
        for (int o = 0; o < OO; o++) {
            float iw = fminf(tr[o][2], bx1) - fmaxf(tr[o][0], bx0);
            float ih = fminf(tr[o][3], by1) - fmaxf(tr[o][1], by0);
            iw = fmaxf(iw, 0.f); ih = fmaxf(ih, 0.f);
            float inter = iw * ih;
            float area_a = (tr[o][2] - tr[o][0]) * (tr[o][3] - tr[o][1]);
            float iou = inter / (area_a + area_b - inter);
            unsigned long long key =
                ((unsigned long long)__float_as_uint(iou) << 32) |
                (unsigned long long)(0xFFFFFFFFu - (unsigned)p);
            if (key > best[o]) best[o] = key;
        }
    }
#pragma unroll
    for (int o = 0; o < OO; o++) {
        unsigned long long v = best[o];
        for (int off = 32; off > 0; off >>= 1) {
            unsigned long long other = __shfl_down(v, off, 64);
            if (other > v) v = other;
        }
        best[o] = v;
    }
    if ((tid & 63) == 0) {
#pragma unroll
        for (int o = 0; o < OO; o++) atomicMax(&skeys[o], best[o]);
    }
    __syncthreads();
    if (tid < OO) atomicMax(&keys[b * OO + tid], skeys[tid]);
}

// ---------------- Phase C: match + encode + smooth-L1 + CE + mined + bin counts ----------------
__device__ __forceinline__ float sl1(float d) {
    float a = fabsf(d);
    return (a < 1.f) ? 0.5f * d * d : a - 0.5f;
}

__global__ __launch_bounds__(256) void mb_phaseC(const float* __restrict__ loc_data,
                                                 const float* __restrict__ conf_data,
                                                 const float* __restrict__ priors,
                                                 const float* __restrict__ targets,
                                                 const unsigned long long* __restrict__ keys,
                                                 float* __restrict__ mined,
                                                 unsigned* __restrict__ hist,
                                                 int* __restrict__ num_pos,
                                                 double* __restrict__ posCE,
                                                 double* __restrict__ loss_l_acc) {
    int b = blockIdx.y, tid = threadIdx.x;
    int wave = tid >> 6, lane = tid & 63;
    int p = blockIdx.x * 256 + tid;

    __shared__ float confs[4][64 * CC];   // 21504 B
    __shared__ float tr[OO][4];
    __shared__ float lab[OO];
    __shared__ unsigned bps[OO];
    __shared__ float redf[8];
    __shared__ int redi[4];

    if (tid < OO * 5) {
        int o = tid / 5, c = tid % 5;
        float v = targets[((size_t)b * OO + o) * 5 + c];
        if (c < 4) tr[o][c] = v; else lab[o] = v;
    }
    if (tid < OO) bps[tid] = 0xFFFFFFFFu - (unsigned)(keys[b * OO + tid] & 0xFFFFFFFFull);

    // stage this wave's 64 priors x 21 classes; float4 fast path when full tile
    int wbase = blockIdx.x * 256 + wave * 64;
    if (wbase < PP) {
        const float* src = conf_data + ((size_t)b * PP + wbase) * CC;
        float* dst = confs[wave];
        if (wbase + 64 <= PP) {
            const float4* s4 = (const float4*)src;
            float4* d4 = (float4*)dst;
#pragma unroll
            for (int j = 0; j < 336; j += 64) {
                int idx = j + lane;
                if (idx < 336) d4[idx] = s4[idx];
            }
        } else {
            int ndw = (PP - wbase) * CC;
            for (int j = lane; j < ndw; j += 64) dst[j] = src[j];
        }
    }
    __syncthreads();

    float t_lossl = 0.f, t_posce = 0.f;
    int t_pos = 0;

    if (p < PP) {
        float4 pr = ((const float4*)priors)[p];
        float bx0 = pr.x - pr.z * 0.5f, by0 = pr.y - pr.w * 0.5f;
        float bx1 = pr.x + pr.z * 0.5f, by1 = pr.y + pr.w * 0.5f;
        float area_b = (bx1 - bx0) * (by1 - by0);
        float bto = -1.f;
        int bti = 0;
#pragma unroll
        for (int o = 0; o < OO; o++) {
            float iw = fminf(tr[o][2], bx1) - fmaxf(tr[o][0], bx0);
            float ih = fminf(tr[o][3], by1) - fmaxf(tr[o][1], by0);
            iw = fmaxf(iw, 0.f); ih = fmaxf(ih, 0.f);
            float inter = iw * ih;
            float area_a = (tr[o][2] - tr[o][0]) * (tr[o][3] - tr[o][1]);
            float iou = inter / (area_a + area_b - inter);
            if (iou > bto) { bto = iou; bti = o; }   // strict > : argmax first-index
        }
#pragma unroll
        for (int o = 0; o < OO; o++) {
            if (bps[o] == (unsigned)p) { bto = 2.0f; bti = o; }  // ascending o = last-wins
        }
        int conf_t = (bto < THRESHf) ? 0 : (int)lab[bti];
        bool pos = conf_t > 0;

        if (pos) {
            float mx0 = tr[bti][0], my0 = tr[bti][1], mx1 = tr[bti][2], my1 = tr[bti][3];
            float gcx = ((mx0 + mx1) * 0.5f - pr.x) / (VAR0f * pr.z);
            float gcy = ((my0 + my1) * 0.5f - pr.y) / (VAR0f * pr.w);
            float gw = logf((mx1 - mx0) / pr.z) / VAR1f;
            float gh = logf((my1 - my0) / pr.w) / VAR1f;
            float4 ld = ((const float4*)loc_data)[(size_t)b * PP + p];
            t_lossl = sl1(ld.x - gcx) + sl1(ld.y - gcy) + sl1(ld.z - gw) + sl1(ld.w - gh);
            t_pos = 1;
        }

        const float* cp = confs[wave] + lane * CC;   // stride-21 LDS: 2-way bank alias = free
        float m = cp[0];
#pragma unroll
        for (int c = 1; c < CC; c++) m = fmaxf(m, cp[c]);
        float s = 0.f;
#pragma unroll
        for (int c = 0; c < CC; c++) s += expf(cp[c] - m);
        float lse = m + logf(s);
        float ce = lse - cp[conf_t];
        if (pos) t_posce = ce;
        float mv = pos ? 0.f : ce;
        mined[(size_t)b * PP + p] = mv;
        // fire-and-forget count into per-row bin histogram (result unused -> non-blocking)
        atomicAdd(&hist[(size_t)b * HBINS + (__float_as_uint(mv) >> HSHIFT)], 1u);
    }

    // wave shuffle reductions
    for (int off = 32; off > 0; off >>= 1) {
        t_lossl += __shfl_down(t_lossl, off, 64);
        t_posce += __shfl_down(t_posce, off, 64);
        t_pos   += __shfl_down(t_pos, off, 64);
    }
    if (lane == 0) { redf[wave] = t_lossl; redf[4 + wave] = t_posce; redi[wave] = t_pos; }
    __syncthreads();
    if (tid == 0) {
        float ll = redf[0] + redf[1] + redf[2] + redf[3];
        float pc = redf[4] + redf[5] + redf[6] + redf[7];
        int np = redi[0] + redi[1] + redi[2] + redi[3];
        if (ll != 0.f) atomicAdd(loss_l_acc, (double)ll);
        if (pc != 0.f) atomicAdd(&posCE[b], (double)pc);
        if (np) atomicAdd(&num_pos[b], np);
    }
}

// ---------------- Phase D2a: find threshold bin + need per row from global counts ----------------
__global__ __launch_bounds__(256) void mb_phaseD2a(const unsigned* __restrict__ hist,
                                                   const int* __restrict__ num_pos,
                                                   int* __restrict__ selBin,
                                                   int* __restrict__ selNeed) {
    int b = blockIdx.x, tid = threadIdx.x;
    int np = num_pos[b];
    int k = min(3 * np, PP - 1);
    if (k <= 0) {
        if (tid == 0) { selBin[b] = -1; selNeed[b] = 0; }
        return;
    }
    const unsigned* h = hist + (size_t)b * HBINS;
    const int CH = HBINS / 256;   // 32 bins per thread
    __shared__ unsigned cs[256];
    unsigned s = 0;
    for (int j = 0; j < CH; j++) s += h[tid * CH + j];
    cs[tid] = s;
    __syncthreads();
    if (tid == 0) {
        unsigned cum = 0;
        int t = 255;
        for (; t > 0; --t) {
            if (cum + cs[t] >= (unsigned)k) break;
            cum += cs[t];
        }
        int base = t * CH, bin = base;
        unsigned cum2 = cum;
        for (int j = CH - 1; j >= 1; --j) {
            unsigned c = h[base + j];
            if (cum2 + c >= (unsigned)k) { bin = base + j; break; }
            cum2 += c;
        }
        selBin[b] = bin;
        selNeed[b] = k - (int)cum2;   // 1..h[bin]
    }
}

// ---------------- Phase D2b: parallel slice scan -> sum_gt + threshold-bin candidates ----------------
__global__ __launch_bounds__(256) void mb_phaseD2b(const float* __restrict__ mined,
                                                   const int* __restrict__ selBin,
                                                   unsigned* __restrict__ candCnt,
                                                   float* __restrict__ cand,
                                                   double* __restrict__ selSumGt) {
    int b = blockIdx.y, tid = threadIdx.x;
    int bin = selBin[b];
    if (bin < 0) return;
    const float* row = mined + (size_t)b * PP;
    __shared__ double sd[256];
    double sgt = 0.0;
    for (int p = blockIdx.x * 256 + tid; p < PP; p += gridDim.x * 256) {
        float x = row[p];
        int bb = (int)(__float_as_uint(x) >> HSHIFT);
        if (bb > bin) sgt += (double)x;
        else if (bb == bin) {
            unsigned i = atomicAdd(&candCnt[b], 1u);
            if (i < CAND_MAX) cand[(size_t)b * CAND_MAX + i] = x;
        }
    }
    sd[tid] = sgt;
    __syncthreads();
    for (int s2 = 128; s2 > 0; s2 >>= 1) {
        if (tid < s2) sd[tid] += sd[tid + s2];
        __syncthreads();
    }
    if (tid == 0 && sd[0] != 0.0) atomicAdd(&selSumGt[b], sd[0]);
}

// ---------------- Phase D2c: in-bin exact rank-select + finalize loss_c per row ----------------
__global__ __launch_bounds__(256) void mb_phaseD2c(const float* __restrict__ mined,
                                                   const int* __restrict__ selBin,
                                                   const int* __restrict__ selNeed,
                                                   const unsigned* __restrict__ candCnt,
                                                   const float* __restrict__ candG,
                                                   const double* __restrict__ selSumGt,
                                                   const int* __restrict__ num_pos,
                                                   const double* __restrict__ posCE,
                                                   double* __restrict__ loss_c_acc) {
    int b = blockIdx.x, tid = threadIdx.x;
    int bin = selBin[b];
    if (bin < 0) {
        if (tid == 0) atomicAdd(loss_c_acc, posCE[b]);
        return;
    }
    int need = selNeed[b];
    unsigned nAll = candCnt[b];
    __shared__ double sd[256];

    if (nAll <= CAND_MAX) {
        __shared__ float cand[CAND_MAX];
        int n = (int)nAll;
        for (int i = tid; i < n; i += 256) cand[i] = candG[(size_t)b * CAND_MAX + i];
        __syncthreads();
        // exact rank-select: include candidate i iff stable-rank < need (ties sum identically)
        double st = 0.0;
        for (int i = tid; i < n; i += 256) {
            float v = cand[i];
            int r = 0;
            for (int j = 0; j < n; j++) {
                float w = cand[j];
                r += (w > v) || (w == v && j < i);
            }
            if (r < need) st += (double)v;
        }
        sd[tid] = st;
        __syncthreads();
        for (int s2 = 128; s2 > 0; s2 >>= 1) {
            if (tid < s2) sd[tid] += sd[tid + s2];
            __syncthreads();
        }
        if (tid == 0) atomicAdd(loss_c_acc, posCE[b] + selSumGt[b] + sd[0]);
    } else {
        // fallback: known-correct 4-pass byte radix select over full 32 bits of the row
        const float* row = mined + (size_t)b * PP;
        int k = min(3 * num_pos[b], PP - 1);
        __shared__ unsigned rhist[256];
        __shared__ unsigned s_prefix;
        __shared__ int s_needed;
        unsigned prefix = 0;
        int needed = k;
        for (int pass = 0; pass < 4; pass++) {
            int shift = 24 - 8 * pass;
            for (int i = tid; i < 256; i += 256) rhist[i] = 0;
            __syncthreads();
            unsigned hi_mask = (pass == 0) ? 0u : (0xFFFFFFFFu << (shift + 8));
            for (int p = tid; p < PP; p += 256) {
                unsigned x = __float_as_uint(row[p]);
                if ((x & hi_mask) == (prefix & hi_mask))
                    atomicAdd(&rhist[(x >> shift) & 0xFFu], 1u);
            }
            __syncthreads();
            if (tid == 0) {
                unsigned cum = 0; int bsel = 0;
                for (int j = 255; j >= 0; j--) {
                    if (cum + rhist[j] >= (unsigned)needed) { bsel = j; break; }
                    cum += rhist[j];
                }
                s_prefix = prefix | ((unsigned)bsel << shift);
                s_needed = needed - (int)cum;
            }
            __syncthreads();
            prefix = s_prefix;
            needed = s_needed;
            __syncthreads();
        }
        float t = __uint_as_float(prefix);
        double sum_gt = 0.0;
        for (int p = tid; p < PP; p += 256) {
            float x = row[p];
            if (__float_as_uint(x) > prefix) sum_gt += (double)x;
        }
        sd[tid] = sum_gt;
        __syncthreads();
        for (int s2 = 128; s2 > 0; s2 >>= 1) {
            if (tid < s2) sd[tid] += sd[tid + s2];
            __syncthreads();
        }
        if (tid == 0)
            atomicAdd(loss_c_acc, posCE[b] + sd[0] + (double)needed * (double)t);
    }
}

// ---------------- Phase E: finalize ----------------
__global__ __launch_bounds__(128) void mb_phaseE(const int* __restrict__ num_pos,
                                                 const double* __restrict__ loss_l_acc,
                                                 const double* __restrict__ loss_c_acc,
                                                 float* __restrict__ out) {
    __shared__ int si[128];
    int tid = threadIdx.x;
    si[tid] = (tid < BB) ? num_pos[tid] : 0;
    __syncthreads();
    for (int s = 64; s > 0; s >>= 1) {
        if (tid < s) si[tid] += si[tid + s];
        __syncthreads();
    }
    if (tid == 0) {
        int n = si[0];
        double N = (n > 0) ? (double)n : (double)BB;
        out[0] = (float)(*loss_l_acc / N);
        out[1] = (float)(*loss_c_acc / N);
    }
}

extern "C" void kernel_launch(void* const* d_in, const int* in_sizes, int n_in,
                              void* d_out, int out_size, void* d_ws, size_t ws_size,
                              hipStream_t stream) {
    const float* loc_data  = (const float*)d_in[0];
    const float* conf_data = (const float*)d_in[1];
    const float* priors    = (const float*)d_in[2];
    const float* targets   = (const float*)d_in[3];

    char* ws = (char*)d_ws;
    // layout: [0..8) loss_l, [8..16) loss_c, [64..576) num_pos[B],
    //         [1024..2048) posCE[B], [2048..18432) keys[B*16] u64,
    //         [18432..18944) candCnt[B] u32, [18944..19456) selBin[B],
    //         [19456..19968) selNeed[B], [19968..20992) selSumGt[B] f64,
    //         [32768..32768+4MB) hist[B*8192] u32,
    //         then cand[B*2048] f32 (1MB), then mined[B*P] f32
    double*             loss_l   = (double*)(ws + 0);
    double*             loss_c   = (double*)(ws + 8);
    int*                num_pos  = (int*)(ws + 64);
    double*             posCE    = (double*)(ws + 1024);
    unsigned long long* keys     = (unsigned long long*)(ws + 2048);
    unsigned*           candCnt  = (unsigned*)(ws + 18432);
    int*                selBin   = (int*)(ws + 18944);
    int*                selNeed  = (int*)(ws + 19456);
    double*             selSumGt = (double*)(ws + 19968);
    unsigned*           hist     = (unsigned*)(ws + 32768);
    float*              cand     = (float*)(ws + 32768 + (size_t)BB * HBINS * 4);
    float*              mined    = (float*)(ws + 32768 + (size_t)BB * HBINS * 4
                                               + (size_t)BB * CAND_MAX * 4);

    hipMemsetAsync(ws, 0, 32768 + (size_t)BB * HBINS * 4, stream);

    mb_phaseA<<<dim3(8, BB), 256, 0, stream>>>(priors, targets, keys);

    dim3 gridC((PP + 255) / 256, BB);
    mb_phaseC<<<gridC, 256, 0, stream>>>(loc_data, conf_data, priors, targets, keys,
                                         mined, hist, num_pos, posCE, loss_l);

    mb_phaseD2a<<<BB, 256, 0, stream>>>(hist, num_pos, selBin, selNeed);

    mb_phaseD2b<<<dim3(16, BB), 256, 0, stream>>>(mined, selBin, candCnt, cand, selSumGt);

    mb_phaseD2c<<<BB, 256, 0, stream>>>(mined, selBin, selNeed, candCnt, cand,
                                        selSumGt, num_pos, posCE, loss_c);

    mb_phaseE<<<1, 128, 0, stream>>>(num_pos, loss_l, loss_c, (float*)d_out);
}

// Round 3
// 1047.229 us; speedup vs baseline: 1.1140x; 1.1140x over previous
//
#include <hip/hip_runtime.h>
#include <math.h>

#define BB 128
#define PP 34125
#define OO 16
#define CC 21
#define HBINS 8192
#define HSHIFT 18
#define CAND_MAX 2048
#define VAR0f 0.1f
#define VAR1f 0.2f
#define THRESHf 0.35f

// ---------------- Phase A: best prior per truth (argmax over P), 8 blocks/row ----------------
__global__ __launch_bounds__(256) void mb_phaseA(const float* __restrict__ priors,
                                                 const float* __restrict__ targets,
                                                 unsigned long long* __restrict__ keys) {
    int b = blockIdx.y, tid = threadIdx.x;
    __shared__ float tr[OO][4];
    __shared__ unsigned long long skeys[OO];
    if (tid < OO * 5) {
        int o = tid / 5, c = tid % 5;
        float v = targets[((size_t)b * OO + o) * 5 + c];
        if (c < 4) tr[o][c] = v;
    }
    if (tid < OO) skeys[tid] = 0ull;
    __syncthreads();

    unsigned long long best[OO];
#pragma unroll
    for (int o = 0; o < OO; o++) best[o] = 0ull;

    for (int p = blockIdx.x * 256 + tid; p < PP; p += gridDim.x * 256) {
        float4 pr = ((const float4*)priors)[p];
        float bx0 = pr.x - pr.z * 0.5f, by0 = pr.y - pr.w * 0.5f;
        float bx1 = pr.x + pr.z * 0.5f, by1 = pr.y + pr.w * 0.5f;
        float area_b = (bx1 - bx0) * (by1 - by0);
#pragma unroll
        for (int o = 0; o < OO; o++) {
            float iw = fminf(tr[o][2], bx1) - fmaxf(tr[o][0], bx0);
            float ih = fminf(tr[o][3], by1) - fmaxf(tr[o][1], by0);
            iw = fmaxf(iw, 0.f); ih = fmaxf(ih, 0.f);
            float inter = iw * ih;
            float area_a = (tr[o][2] - tr[o][0]) * (tr[o][3] - tr[o][1]);
            float iou = inter / (area_a + area_b - inter);
            unsigned long long key =
                ((unsigned long long)__float_as_uint(iou) << 32) |
                (unsigned long long)(0xFFFFFFFFu - (unsigned)p);
            if (key > best[o]) best[o] = key;
        }
    }
#pragma unroll
    for (int o = 0; o < OO; o++) {
        unsigned long long v = best[o];
        for (int off = 32; off > 0; off >>= 1) {
            unsigned long long other = __shfl_down(v, off, 64);
            if (other > v) v = other;
        }
        best[o] = v;
    }
    if ((tid & 63) == 0) {
#pragma unroll
        for (int o = 0; o < OO; o++) atomicMax(&skeys[o], best[o]);
    }
    __syncthreads();
    if (tid < OO) atomicMax(&keys[b * OO + tid], skeys[tid]);
}

// ---------------- Phase C: match + encode + smooth-L1 + CE + mined ----------------
// T14 async-STAGE split: conf tile -> registers, IoU/match phase runs while loads are in
// flight, LDS commit + barrier only before the softmax that needs the tile.
__device__ __forceinline__ float sl1(float d) {
    float a = fabsf(d);
    return (a < 1.f) ? 0.5f * d * d : a - 0.5f;
}

__global__ __launch_bounds__(256) void mb_phaseC(const float* __restrict__ loc_data,
                                                 const float* __restrict__ conf_data,
                                                 const float* __restrict__ priors,
                                                 const float* __restrict__ targets,
                                                 const unsigned long long* __restrict__ keys,
                                                 float* __restrict__ mined,
                                                 int* __restrict__ num_pos,
                                                 double* __restrict__ posCE,
                                                 double* __restrict__ loss_l_acc) {
    int b = blockIdx.y, tid = threadIdx.x;
    int wave = tid >> 6, lane = tid & 63;
    int p = blockIdx.x * 256 + tid;

    __shared__ float confs[4][64 * CC];   // 21504 B
    __shared__ float tr[OO][4];
    __shared__ float lab[OO];
    __shared__ unsigned bps[OO];
    __shared__ float redf[8];
    __shared__ int redi[4];

    if (tid < OO * 5) {
        int o = tid / 5, c = tid % 5;
        float v = targets[((size_t)b * OO + o) * 5 + c];
        if (c < 4) tr[o][c] = v; else lab[o] = v;
    }
    if (tid < OO) bps[tid] = 0xFFFFFFFFu - (unsigned)(keys[b * OO + tid] & 0xFFFFFFFFull);
    // barrier BEFORE issuing staging loads: drains nothing, publishes tr/lab/bps
    __syncthreads();

    // ---- issue conf staging loads into registers (fire now, commit to LDS later) ----
    int wbase = blockIdx.x * 256 + wave * 64;
    const float* src = conf_data + ((size_t)b * PP + wbase) * CC;
    float4 creg0, creg1, creg2, creg3, creg4, creg5;
    bool fullTile = (wbase + 64 <= PP);
    if (fullTile) {
        const float4* s4 = (const float4*)src;
        creg0 = s4[0 * 64 + lane];
        creg1 = s4[1 * 64 + lane];
        creg2 = s4[2 * 64 + lane];
        creg3 = s4[3 * 64 + lane];
        creg4 = s4[4 * 64 + lane];
        if (lane < 16) creg5 = s4[320 + lane];
    }

    // ---- IoU / match / encode / smooth-L1 while conf loads are in flight ----
    float t_lossl = 0.f, t_posce = 0.f;
    int t_pos = 0;
    int conf_t = 0;
    bool valid = (p < PP);

    if (valid) {
        float4 pr = ((const float4*)priors)[p];
        float bx0 = pr.x - pr.z * 0.5f, by0 = pr.y - pr.w * 0.5f;
        float bx1 = pr.x + pr.z * 0.5f, by1 = pr.y + pr.w * 0.5f;
        float area_b = (bx1 - bx0) * (by1 - by0);
        float bto = -1.f;
        int bti = 0;
#pragma unroll
        for (int o = 0; o < OO; o++) {
            float iw = fminf(tr[o][2], bx1) - fmaxf(tr[o][0], bx0);
            float ih = fminf(tr[o][3], by1) - fmaxf(tr[o][1], by0);
            iw = fmaxf(iw, 0.f); ih = fmaxf(ih, 0.f);
            float inter = iw * ih;
            float area_a = (tr[o][2] - tr[o][0]) * (tr[o][3] - tr[o][1]);
            float iou = inter / (area_a + area_b - inter);
            if (iou > bto) { bto = iou; bti = o; }   // strict > : argmax first-index
        }
#pragma unroll
        for (int o = 0; o < OO; o++) {
            if (bps[o] == (unsigned)p) { bto = 2.0f; bti = o; }  // ascending o = last-wins
        }
        conf_t = (bto < THRESHf) ? 0 : (int)lab[bti];
        bool pos = conf_t > 0;

        if (pos) {
            float mx0 = tr[bti][0], my0 = tr[bti][1], mx1 = tr[bti][2], my1 = tr[bti][3];
            float gcx = ((mx0 + mx1) * 0.5f - pr.x) / (VAR0f * pr.z);
            float gcy = ((my0 + my1) * 0.5f - pr.y) / (VAR0f * pr.w);
            float gw = __logf((mx1 - mx0) / pr.z) / VAR1f;
            float gh = __logf((my1 - my0) / pr.w) / VAR1f;
            float4 ld = ((const float4*)loc_data)[(size_t)b * PP + p];
            t_lossl = sl1(ld.x - gcx) + sl1(ld.y - gcy) + sl1(ld.z - gw) + sl1(ld.w - gh);
            t_pos = 1;
        }
    }

    // ---- commit staged conf tile to LDS ----
    if (fullTile) {
        float4* d4 = (float4*)confs[wave];
        d4[0 * 64 + lane] = creg0;
        d4[1 * 64 + lane] = creg1;
        d4[2 * 64 + lane] = creg2;
        d4[3 * 64 + lane] = creg3;
        d4[4 * 64 + lane] = creg4;
        if (lane < 16) d4[320 + lane] = creg5;
    } else if (wbase < PP) {
        int ndw = (PP - wbase) * CC;
        float* dst = confs[wave];
        for (int j = lane; j < ndw; j += 64) dst[j] = src[j];
    }
    __syncthreads();

    // ---- softmax CE from LDS tile ----
    if (valid) {
        const float* cp = confs[wave] + lane * CC;   // stride-21 LDS: 2-way bank alias = free
        float m = cp[0];
#pragma unroll
        for (int c = 1; c < CC; c++) m = fmaxf(m, cp[c]);
        float s = 0.f;
#pragma unroll
        for (int c = 0; c < CC; c++) s += __expf(cp[c] - m);
        float lse = m + __logf(s);
        float ce = lse - cp[conf_t];
        bool pos = conf_t > 0;
        if (pos) t_posce = ce;
        mined[(size_t)b * PP + p] = pos ? 0.f : ce;
    }

    // wave shuffle reductions
    for (int off = 32; off > 0; off >>= 1) {
        t_lossl += __shfl_down(t_lossl, off, 64);
        t_posce += __shfl_down(t_posce, off, 64);
        t_pos   += __shfl_down(t_pos, off, 64);
    }
    if (lane == 0) { redf[wave] = t_lossl; redf[4 + wave] = t_posce; redi[wave] = t_pos; }
    __syncthreads();
    if (tid == 0) {
        float ll = redf[0] + redf[1] + redf[2] + redf[3];
        float pc = redf[4] + redf[5] + redf[6] + redf[7];
        int np = redi[0] + redi[1] + redi[2] + redi[3];
        if (ll != 0.f) atomicAdd(loss_l_acc, (double)ll);
        if (pc != 0.f) atomicAdd(&posCE[b], (double)pc);
        if (np) atomicAdd(&num_pos[b], np);
    }
}

// ---------------- Phase D1: 16 blocks/row, private LDS histogram, sparse flush ----------------
__global__ __launch_bounds__(256) void mb_phaseD1(const float* __restrict__ mined,
                                                  unsigned* __restrict__ hist) {
    int b = blockIdx.y, tid = threadIdx.x;
    __shared__ unsigned lh[HBINS];   // 32 KB
    for (int i = tid; i < HBINS; i += 256) lh[i] = 0;
    __syncthreads();
    const float* row = mined + (size_t)b * PP;
    for (int p = blockIdx.x * 256 + tid; p < PP; p += gridDim.x * 256)
        atomicAdd(&lh[__float_as_uint(row[p]) >> HSHIFT], 1u);
    __syncthreads();
    unsigned* gh = hist + (size_t)b * HBINS;
    for (int i = tid; i < HBINS; i += 256) {
        unsigned c = lh[i];
        if (c) atomicAdd(&gh[i], c);   // fire-and-forget at kernel end, no barrier after
    }
}

// ---------------- Phase D2a: find threshold bin + need per row from global counts ----------------
__global__ __launch_bounds__(256) void mb_phaseD2a(const unsigned* __restrict__ hist,
                                                   const int* __restrict__ num_pos,
                                                   int* __restrict__ selBin,
                                                   int* __restrict__ selNeed) {
    int b = blockIdx.x, tid = threadIdx.x;
    int np = num_pos[b];
    int k = min(3 * np, PP - 1);
    if (k <= 0) {
        if (tid == 0) { selBin[b] = -1; selNeed[b] = 0; }
        return;
    }
    const unsigned* h = hist + (size_t)b * HBINS;
    const int CH = HBINS / 256;   // 32 bins per thread
    __shared__ unsigned cs[256];
    unsigned s = 0;
    for (int j = 0; j < CH; j++) s += h[tid * CH + j];
    cs[tid] = s;
    __syncthreads();
    if (tid == 0) {
        unsigned cum = 0;
        int t = 255;
        for (; t > 0; --t) {
            if (cum + cs[t] >= (unsigned)k) break;
            cum += cs[t];
        }
        int base = t * CH, bin = base;
        unsigned cum2 = cum;
        for (int j = CH - 1; j >= 1; --j) {
            unsigned c = h[base + j];
            if (cum2 + c >= (unsigned)k) { bin = base + j; break; }
            cum2 += c;
        }
        selBin[b] = bin;
        selNeed[b] = k - (int)cum2;   // 1..h[bin]
    }
}

// ---------------- Phase D2b: parallel slice scan -> sum_gt + threshold-bin candidates ----------------
__global__ __launch_bounds__(256) void mb_phaseD2b(const float* __restrict__ mined,
                                                   const int* __restrict__ selBin,
                                                   unsigned* __restrict__ candCnt,
                                                   float* __restrict__ cand,
                                                   double* __restrict__ selSumGt) {
    int b = blockIdx.y, tid = threadIdx.x;
    int bin = selBin[b];
    if (bin < 0) return;
    const float* row = mined + (size_t)b * PP;
    __shared__ double sd[256];
    double sgt = 0.0;
    for (int p = blockIdx.x * 256 + tid; p < PP; p += gridDim.x * 256) {
        float x = row[p];
        int bb = (int)(__float_as_uint(x) >> HSHIFT);
        if (bb > bin) sgt += (double)x;
        else if (bb == bin) {
            unsigned i = atomicAdd(&candCnt[b], 1u);
            if (i < CAND_MAX) cand[(size_t)b * CAND_MAX + i] = x;
        }
    }
    sd[tid] = sgt;
    __syncthreads();
    for (int s2 = 128; s2 > 0; s2 >>= 1) {
        if (tid < s2) sd[tid] += sd[tid + s2];
        __syncthreads();
    }
    if (tid == 0 && sd[0] != 0.0) atomicAdd(&selSumGt[b], sd[0]);
}

// ---------------- Phase D2c: in-bin exact rank-select + finalize loss_c per row ----------------
__global__ __launch_bounds__(256) void mb_phaseD2c(const float* __restrict__ mined,
                                                   const int* __restrict__ selBin,
                                                   const int* __restrict__ selNeed,
                                                   const unsigned* __restrict__ candCnt,
                                                   const float* __restrict__ candG,
                                                   const double* __restrict__ selSumGt,
                                                   const int* __restrict__ num_pos,
                                                   const double* __restrict__ posCE,
                                                   double* __restrict__ loss_c_acc) {
    int b = blockIdx.x, tid = threadIdx.x;
    int bin = selBin[b];
    if (bin < 0) {
        if (tid == 0) atomicAdd(loss_c_acc, posCE[b]);
        return;
    }
    int need = selNeed[b];
    unsigned nAll = candCnt[b];
    __shared__ double sd[256];

    if (nAll <= CAND_MAX) {
        __shared__ float cand[CAND_MAX];
        int n = (int)nAll;
        for (int i = tid; i < n; i += 256) cand[i] = candG[(size_t)b * CAND_MAX + i];
        __syncthreads();
        // exact rank-select: include candidate i iff stable-rank < need (ties sum identically)
        double st = 0.0;
        for (int i = tid; i < n; i += 256) {
            float v = cand[i];
            int r = 0;
            for (int j = 0; j < n; j++) {
                float w = cand[j];
                r += (w > v) || (w == v && j < i);
            }
            if (r < need) st += (double)v;
        }
        sd[tid] = st;
        __syncthreads();
        for (int s2 = 128; s2 > 0; s2 >>= 1) {
            if (tid < s2) sd[tid] += sd[tid + s2];
            __syncthreads();
        }
        if (tid == 0) atomicAdd(loss_c_acc, posCE[b] + selSumGt[b] + sd[0]);
    } else {
        // fallback: known-correct 4-pass byte radix select over full 32 bits of the row
        const float* row = mined + (size_t)b * PP;
        int k = min(3 * num_pos[b], PP - 1);
        __shared__ unsigned rhist[256];
        __shared__ unsigned s_prefix;
        __shared__ int s_needed;
        unsigned prefix = 0;
        int needed = k;
        for (int pass = 0; pass < 4; pass++) {
            int shift = 24 - 8 * pass;
            for (int i = tid; i < 256; i += 256) rhist[i] = 0;
            __syncthreads();
            unsigned hi_mask = (pass == 0) ? 0u : (0xFFFFFFFFu << (shift + 8));
            for (int p = tid; p < PP; p += 256) {
                unsigned x = __float_as_uint(row[p]);
                if ((x & hi_mask) == (prefix & hi_mask))
                    atomicAdd(&rhist[(x >> shift) & 0xFFu], 1u);
            }
            __syncthreads();
            if (tid == 0) {
                unsigned cum = 0; int bsel = 0;
                for (int j = 255; j >= 0; j--) {
                    if (cum + rhist[j] >= (unsigned)needed) { bsel = j; break; }
                    cum += rhist[j];
                }
                s_prefix = prefix | ((unsigned)bsel << shift);
                s_needed = needed - (int)cum;
            }
            __syncthreads();
            prefix = s_prefix;
            needed = s_needed;
            __syncthreads();
        }
        float t = __uint_as_float(prefix);
        double sum_gt = 0.0;
        for (int p = tid; p < PP; p += 256) {
            float x = row[p];
            if (__float_as_uint(x) > prefix) sum_gt += (double)x;
        }
        sd[tid] = sum_gt;
        __syncthreads();
        for (int s2 = 128; s2 > 0; s2 >>= 1) {
            if (tid < s2) sd[tid] += sd[tid + s2];
            __syncthreads();
        }
        if (tid == 0)
            atomicAdd(loss_c_acc, posCE[b] + sd[0] + (double)needed * (double)t);
    }
}

// ---------------- Phase E: finalize ----------------
__global__ __launch_bounds__(128) void mb_phaseE(const int* __restrict__ num_pos,
                                                 const double* __restrict__ loss_l_acc,
                                                 const double* __restrict__ loss_c_acc,
                                                 float* __restrict__ out) {
    __shared__ int si[128];
    int tid = threadIdx.x;
    si[tid] = (tid < BB) ? num_pos[tid] : 0;
    __syncthreads();
    for (int s = 64; s > 0; s >>= 1) {
        if (tid < s) si[tid] += si[tid + s];
        __syncthreads();
    }
    if (tid == 0) {
        int n = si[0];
        double N = (n > 0) ? (double)n : (double)BB;
        out[0] = (float)(*loss_l_acc / N);
        out[1] = (float)(*loss_c_acc / N);
    }
}

extern "C" void kernel_launch(void* const* d_in, const int* in_sizes, int n_in,
                              void* d_out, int out_size, void* d_ws, size_t ws_size,
                              hipStream_t stream) {
    const float* loc_data  = (const float*)d_in[0];
    const float* conf_data = (const float*)d_in[1];
    const float* priors    = (const float*)d_in[2];
    const float* targets   = (const float*)d_in[3];

    char* ws = (char*)d_ws;
    // layout: [0..8) loss_l, [8..16) loss_c, [64..576) num_pos[B],
    //         [1024..2048) posCE[B], [2048..18432) keys[B*16] u64,
    //         [18432..18944) candCnt[B] u32, [18944..19456) selBin[B],
    //         [19456..19968) selNeed[B], [19968..20992) selSumGt[B] f64,
    //         [32768..32768+4MB) hist[B*8192] u32,
    //         then cand[B*2048] f32 (1MB), then mined[B*P] f32
    double*             loss_l   = (double*)(ws + 0);
    double*             loss_c   = (double*)(ws + 8);
    int*                num_pos  = (int*)(ws + 64);
    double*             posCE    = (double*)(ws + 1024);
    unsigned long long* keys     = (unsigned long long*)(ws + 2048);
    unsigned*           candCnt  = (unsigned*)(ws + 18432);
    int*                selBin   = (int*)(ws + 18944);
    int*                selNeed  = (int*)(ws + 19456);
    double*             selSumGt = (double*)(ws + 19968);
    unsigned*           hist     = (unsigned*)(ws + 32768);
    float*              cand     = (float*)(ws + 32768 + (size_t)BB * HBINS * 4);
    float*              mined    = (float*)(ws + 32768 + (size_t)BB * HBINS * 4
                                               + (size_t)BB * CAND_MAX * 4);

    hipMemsetAsync(ws, 0, 32768 + (size_t)BB * HBINS * 4, stream);

    mb_phaseA<<<dim3(8, BB), 256, 0, stream>>>(priors, targets, keys);

    dim3 gridC((PP + 255) / 256, BB);
    mb_phaseC<<<gridC, 256, 0, stream>>>(loc_data, conf_data, priors, targets, keys,
                                         mined, num_pos, posCE, loss_l);

    mb_phaseD1<<<dim3(16, BB), 256, 0, stream>>>(mined, hist);

    mb_phaseD2a<<<BB, 256, 0, stream>>>(hist, num_pos, selBin, selNeed);

    mb_phaseD2b<<<dim3(16, BB), 256, 0, stream>>>(mined, selBin, candCnt, cand, selSumGt);

    mb_phaseD2c<<<BB, 256, 0, stream>>>(mined, selBin, selNeed, candCnt, cand,
                                        selSumGt, num_pos, posCE, loss_c);

    mb_phaseE<<<1, 128, 0, stream>>>(num_pos, loss_l, loss_c, (float*)d_out);
}

// Round 4
// 1045.838 us; speedup vs baseline: 1.1155x; 1.0013x over previous
//
#include <hip/hip_runtime.h>
#include <math.h>

#define BB 128
#define PP 34125
#define OO 16
#define CC 21
#define HBINS 8192
#define HSHIFT 18
#define CAND_MAX 2048
#define VAR0f 0.1f
#define VAR1f 0.2f
#define THRESHf 0.35f

// ---------------- Phase A: best prior per truth (argmax over P), 8 blocks/row ----------------
__global__ __launch_bounds__(256) void mb_phaseA(const float* __restrict__ priors,
                                                 const float* __restrict__ targets,
                                                 unsigned long long* __restrict__ keys) {
    int b = blockIdx.y, tid = threadIdx.x;
    __shared__ float tr[OO][4];
    __shared__ unsigned long long skeys[OO];
    if (tid < OO * 5) {
        int o = tid / 5, c = tid % 5;
        float v = targets[((size_t)b * OO + o) * 5 + c];
        if (c < 4) tr[o][c] = v;
    }
    if (tid < OO) skeys[tid] = 0ull;
    __syncthreads();

    unsigned long long best[OO];
#pragma unroll
    for (int o = 0; o < OO; o++) best[o] = 0ull;

    for (int p = blockIdx.x * 256 + tid; p < PP; p += gridDim.x * 256) {
        float4 pr = ((const float4*)priors)[p];
        float bx0 = pr.x - pr.z * 0.5f, by0 = pr.y - pr.w * 0.5f;
        float bx1 = pr.x + pr.z * 0.5f, by1 = pr.y + pr.w * 0.5f;
        float area_b = (bx1 - bx0) * (by1 - by0);
#pragma unroll
        for (int o = 0; o < OO; o++) {
            float iw = fminf(tr[o][2], bx1) - fmaxf(tr[o][0], bx0);
            float ih = fminf(tr[o][3], by1) - fmaxf(tr[o][1], by0);
            iw = fmaxf(iw, 0.f); ih = fmaxf(ih, 0.f);
            float inter = iw * ih;
            float area_a = (tr[o][2] - tr[o][0]) * (tr[o][3] - tr[o][1]);
            float iou = inter / (area_a + area_b - inter);
            unsigned long long key =
                ((unsigned long long)__float_as_uint(iou) << 32) |
                (unsigned long long)(0xFFFFFFFFu - (unsigned)p);
            if (key > best[o]) best[o] = key;
        }
    }
#pragma unroll
    for (int o = 0; o < OO; o++) {
        unsigned long long v = best[o];
        for (int off = 32; off > 0; off >>= 1) {
            unsigned long long other = __shfl_down(v, off, 64);
            if (other > v) v = other;
        }
        best[o] = v;
    }
    if ((tid & 63) == 0) {
#pragma unroll
        for (int o = 0; o < OO; o++) atomicMax(&skeys[o], best[o]);
    }
    __syncthreads();
    if (tid < OO) atomicMax(&keys[b * OO + tid], skeys[tid]);
}

// ---------------- Phase C: match + encode + smooth-L1 + CE + mined ----------------
// Direct-global softmax: each thread reads its own 21 contiguous conf floats into
// registers at kernel top (they land under the IoU/match phase). No conf LDS tile,
// no mid-kernel barriers, no bank conflicts; occupancy no longer LDS-capped.
__device__ __forceinline__ float sl1(float d) {
    float a = fabsf(d);
    return (a < 1.f) ? 0.5f * d * d : a - 0.5f;
}

__global__ __launch_bounds__(256) void mb_phaseC(const float* __restrict__ loc_data,
                                                 const float* __restrict__ conf_data,
                                                 const float* __restrict__ priors,
                                                 const float* __restrict__ targets,
                                                 const unsigned long long* __restrict__ keys,
                                                 float* __restrict__ mined,
                                                 int* __restrict__ num_pos,
                                                 double* __restrict__ posCE,
                                                 double* __restrict__ loss_l_acc) {
    int b = blockIdx.y, tid = threadIdx.x;
    int wave = tid >> 6, lane = tid & 63;
    int p = blockIdx.x * 256 + tid;

    __shared__ float tr[OO][4];
    __shared__ float lab[OO];
    __shared__ unsigned bps[OO];
    __shared__ float redf[8];
    __shared__ int redi[4];

    if (tid < OO * 5) {
        int o = tid / 5, c = tid % 5;
        float v = targets[((size_t)b * OO + o) * 5 + c];
        if (c < 4) tr[o][c] = v; else lab[o] = v;
    }
    if (tid < OO) bps[tid] = 0xFFFFFFFFu - (unsigned)(keys[b * OO + tid] & 0xFFFFFFFFull);
    // only barrier before the tail reduction: publishes tr/lab/bps, drains nothing heavy
    __syncthreads();

    float t_lossl = 0.f, t_posce = 0.f;
    int t_pos = 0;
    bool valid = (p < PP);

    // ---- issue this thread's 21 conf loads immediately (all-static reg indices) ----
    float creg[CC];
    if (valid) {
        const float* src = conf_data + ((size_t)b * PP + p) * CC;
#pragma unroll
        for (int c = 0; c < CC; c++) creg[c] = src[c];
    }

    if (valid) {
        // ---- IoU / match / encode / smooth-L1 while conf loads are in flight ----
        float4 pr = ((const float4*)priors)[p];
        float bx0 = pr.x - pr.z * 0.5f, by0 = pr.y - pr.w * 0.5f;
        float bx1 = pr.x + pr.z * 0.5f, by1 = pr.y + pr.w * 0.5f;
        float area_b = (bx1 - bx0) * (by1 - by0);
        float bto = -1.f;
        int bti = 0;
#pragma unroll
        for (int o = 0; o < OO; o++) {
            float iw = fminf(tr[o][2], bx1) - fmaxf(tr[o][0], bx0);
            float ih = fminf(tr[o][3], by1) - fmaxf(tr[o][1], by0);
            iw = fmaxf(iw, 0.f); ih = fmaxf(ih, 0.f);
            float inter = iw * ih;
            float area_a = (tr[o][2] - tr[o][0]) * (tr[o][3] - tr[o][1]);
            float iou = inter / (area_a + area_b - inter);
            if (iou > bto) { bto = iou; bti = o; }   // strict > : argmax first-index
        }
#pragma unroll
        for (int o = 0; o < OO; o++) {
            if (bps[o] == (unsigned)p) { bto = 2.0f; bti = o; }  // ascending o = last-wins
        }
        int conf_t = (bto < THRESHf) ? 0 : (int)lab[bti];
        bool pos = conf_t > 0;

        if (pos) {
            float mx0 = tr[bti][0], my0 = tr[bti][1], mx1 = tr[bti][2], my1 = tr[bti][3];
            float gcx = ((mx0 + mx1) * 0.5f - pr.x) / (VAR0f * pr.z);
            float gcy = ((my0 + my1) * 0.5f - pr.y) / (VAR0f * pr.w);
            float gw = __logf((mx1 - mx0) / pr.z) / VAR1f;
            float gh = __logf((my1 - my0) / pr.w) / VAR1f;
            float4 ld = ((const float4*)loc_data)[(size_t)b * PP + p];
            t_lossl = sl1(ld.x - gcx) + sl1(ld.y - gcy) + sl1(ld.z - gw) + sl1(ld.w - gh);
            t_pos = 1;
        }

        // ---- softmax CE from registers (same op order as verified LDS version) ----
        float m = creg[0];
#pragma unroll
        for (int c = 1; c < CC; c++) m = fmaxf(m, creg[c]);
        float s = 0.f;
#pragma unroll
        for (int c = 0; c < CC; c++) s += __expf(creg[c] - m);
        float lse = m + __logf(s);
        // gather creg[conf_t] with static indices only (predicated select chain)
        float gat = creg[0];
#pragma unroll
        for (int c = 1; c < CC; c++) {
            if (c == conf_t) gat = creg[c];
        }
        float ce = lse - gat;
        if (pos) t_posce = ce;
        mined[(size_t)b * PP + p] = pos ? 0.f : ce;
    }

    // wave shuffle reductions
    for (int off = 32; off > 0; off >>= 1) {
        t_lossl += __shfl_down(t_lossl, off, 64);
        t_posce += __shfl_down(t_posce, off, 64);
        t_pos   += __shfl_down(t_pos, off, 64);
    }
    if (lane == 0) { redf[wave] = t_lossl; redf[4 + wave] = t_posce; redi[wave] = t_pos; }
    __syncthreads();
    if (tid == 0) {
        float ll = redf[0] + redf[1] + redf[2] + redf[3];
        float pc = redf[4] + redf[5] + redf[6] + redf[7];
        int np = redi[0] + redi[1] + redi[2] + redi[3];
        if (ll != 0.f) atomicAdd(loss_l_acc, (double)ll);
        if (pc != 0.f) atomicAdd(&posCE[b], (double)pc);
        if (np) atomicAdd(&num_pos[b], np);
    }
}

// ---------------- Phase D1: 16 blocks/row, private LDS histogram, sparse flush ----------------
__global__ __launch_bounds__(256) void mb_phaseD1(const float* __restrict__ mined,
                                                  unsigned* __restrict__ hist) {
    int b = blockIdx.y, tid = threadIdx.x;
    __shared__ unsigned lh[HBINS];   // 32 KB
    for (int i = tid; i < HBINS; i += 256) lh[i] = 0;
    __syncthreads();
    const float* row = mined + (size_t)b * PP;
    for (int p = blockIdx.x * 256 + tid; p < PP; p += gridDim.x * 256)
        atomicAdd(&lh[__float_as_uint(row[p]) >> HSHIFT], 1u);
    __syncthreads();
    unsigned* gh = hist + (size_t)b * HBINS;
    for (int i = tid; i < HBINS; i += 256) {
        unsigned c = lh[i];
        if (c) atomicAdd(&gh[i], c);   // fire-and-forget at kernel end, no barrier after
    }
}

// ---------------- Phase D2a: find threshold bin + need per row from global counts ----------------
__global__ __launch_bounds__(256) void mb_phaseD2a(const unsigned* __restrict__ hist,
                                                   const int* __restrict__ num_pos,
                                                   int* __restrict__ selBin,
                                                   int* __restrict__ selNeed) {
    int b = blockIdx.x, tid = threadIdx.x;
    int np = num_pos[b];
    int k = min(3 * np, PP - 1);
    if (k <= 0) {
        if (tid == 0) { selBin[b] = -1; selNeed[b] = 0; }
        return;
    }
    const unsigned* h = hist + (size_t)b * HBINS;
    const int CH = HBINS / 256;   // 32 bins per thread
    __shared__ unsigned cs[256];
    unsigned s = 0;
    for (int j = 0; j < CH; j++) s += h[tid * CH + j];
    cs[tid] = s;
    __syncthreads();
    if (tid == 0) {
        unsigned cum = 0;
        int t = 255;
        for (; t > 0; --t) {
            if (cum + cs[t] >= (unsigned)k) break;
            cum += cs[t];
        }
        int base = t * CH, bin = base;
        unsigned cum2 = cum;
        for (int j = CH - 1; j >= 1; --j) {
            unsigned c = h[base + j];
            if (cum2 + c >= (unsigned)k) { bin = base + j; break; }
            cum2 += c;
        }
        selBin[b] = bin;
        selNeed[b] = k - (int)cum2;   // 1..h[bin]
    }
}

// ---------------- Phase D2b: parallel slice scan -> sum_gt + threshold-bin candidates ----------------
__global__ __launch_bounds__(256) void mb_phaseD2b(const float* __restrict__ mined,
                                                   const int* __restrict__ selBin,
                                                   unsigned* __restrict__ candCnt,
                                                   float* __restrict__ cand,
                                                   double* __restrict__ selSumGt) {
    int b = blockIdx.y, tid = threadIdx.x;
    int bin = selBin[b];
    if (bin < 0) return;
    const float* row = mined + (size_t)b * PP;
    __shared__ double sd[256];
    double sgt = 0.0;
    for (int p = blockIdx.x * 256 + tid; p < PP; p += gridDim.x * 256) {
        float x = row[p];
        int bb = (int)(__float_as_uint(x) >> HSHIFT);
        if (bb > bin) sgt += (double)x;
        else if (bb == bin) {
            unsigned i = atomicAdd(&candCnt[b], 1u);
            if (i < CAND_MAX) cand[(size_t)b * CAND_MAX + i] = x;
        }
    }
    sd[tid] = sgt;
    __syncthreads();
    for (int s2 = 128; s2 > 0; s2 >>= 1) {
        if (tid < s2) sd[tid] += sd[tid + s2];
        __syncthreads();
    }
    if (tid == 0 && sd[0] != 0.0) atomicAdd(&selSumGt[b], sd[0]);
}

// ---------------- Phase D2c: in-bin exact rank-select + finalize loss_c per row ----------------
__global__ __launch_bounds__(256) void mb_phaseD2c(const float* __restrict__ mined,
                                                   const int* __restrict__ selBin,
                                                   const int* __restrict__ selNeed,
                                                   const unsigned* __restrict__ candCnt,
                                                   const float* __restrict__ candG,
                                                   const double* __restrict__ selSumGt,
                                                   const int* __restrict__ num_pos,
                                                   const double* __restrict__ posCE,
                                                   double* __restrict__ loss_c_acc) {
    int b = blockIdx.x, tid = threadIdx.x;
    int bin = selBin[b];
    if (bin < 0) {
        if (tid == 0) atomicAdd(loss_c_acc, posCE[b]);
        return;
    }
    int need = selNeed[b];
    unsigned nAll = candCnt[b];
    __shared__ double sd[256];

    if (nAll <= CAND_MAX) {
        __shared__ float cand[CAND_MAX];
        int n = (int)nAll;
        for (int i = tid; i < n; i += 256) cand[i] = candG[(size_t)b * CAND_MAX + i];
        __syncthreads();
        // exact rank-select: include candidate i iff stable-rank < need (ties sum identically)
        double st = 0.0;
        for (int i = tid; i < n; i += 256) {
            float v = cand[i];
            int r = 0;
            for (int j = 0; j < n; j++) {
                float w = cand[j];
                r += (w > v) || (w == v && j < i);
            }
            if (r < need) st += (double)v;
        }
        sd[tid] = st;
        __syncthreads();
        for (int s2 = 128; s2 > 0; s2 >>= 1) {
            if (tid < s2) sd[tid] += sd[tid + s2];
            __syncthreads();
        }
        if (tid == 0) atomicAdd(loss_c_acc, posCE[b] + selSumGt[b] + sd[0]);
    } else {
        // fallback: known-correct 4-pass byte radix select over full 32 bits of the row
        const float* row = mined + (size_t)b * PP;
        int k = min(3 * num_pos[b], PP - 1);
        __shared__ unsigned rhist[256];
        __shared__ unsigned s_prefix;
        __shared__ int s_needed;
        unsigned prefix = 0;
        int needed = k;
        for (int pass = 0; pass < 4; pass++) {
            int shift = 24 - 8 * pass;
            for (int i = tid; i < 256; i += 256) rhist[i] = 0;
            __syncthreads();
            unsigned hi_mask = (pass == 0) ? 0u : (0xFFFFFFFFu << (shift + 8));
            for (int p = tid; p < PP; p += 256) {
                unsigned x = __float_as_uint(row[p]);
                if ((x & hi_mask) == (prefix & hi_mask))
                    atomicAdd(&rhist[(x >> shift) & 0xFFu], 1u);
            }
            __syncthreads();
            if (tid == 0) {
                unsigned cum = 0; int bsel = 0;
                for (int j = 255; j >= 0; j--) {
                    if (cum + rhist[j] >= (unsigned)needed) { bsel = j; break; }
                    cum += rhist[j];
                }
                s_prefix = prefix | ((unsigned)bsel << shift);
                s_needed = needed - (int)cum;
            }
            __syncthreads();
            prefix = s_prefix;
            needed = s_needed;
            __syncthreads();
        }
        float t = __uint_as_float(prefix);
        double sum_gt = 0.0;
        for (int p = tid; p < PP; p += 256) {
            float x = row[p];
            if (__float_as_uint(x) > prefix) sum_gt += (double)x;
        }
        sd[tid] = sum_gt;
        __syncthreads();
        for (int s2 = 128; s2 > 0; s2 >>= 1) {
            if (tid < s2) sd[tid] += sd[tid + s2];
            __syncthreads();
        }
        if (tid == 0)
            atomicAdd(loss_c_acc, posCE[b] + sd[0] + (double)needed * (double)t);
    }
}

// ---------------- Phase E: finalize ----------------
__global__ __launch_bounds__(128) void mb_phaseE(const int* __restrict__ num_pos,
                                                 const double* __restrict__ loss_l_acc,
                                                 const double* __restrict__ loss_c_acc,
                                                 float* __restrict__ out) {
    __shared__ int si[128];
    int tid = threadIdx.x;
    si[tid] = (tid < BB) ? num_pos[tid] : 0;
    __syncthreads();
    for (int s = 64; s > 0; s >>= 1) {
        if (tid < s) si[tid] += si[tid + s];
        __syncthreads();
    }
    if (tid == 0) {
        int n = si[0];
        double N = (n > 0) ? (double)n : (double)BB;
        out[0] = (float)(*loss_l_acc / N);
        out[1] = (float)(*loss_c_acc / N);
    }
}

extern "C" void kernel_launch(void* const* d_in, const int* in_sizes, int n_in,
                              void* d_out, int out_size, void* d_ws, size_t ws_size,
                              hipStream_t stream) {
    const float* loc_data  = (const float*)d_in[0];
    const float* conf_data = (const float*)d_in[1];
    const float* priors    = (const float*)d_in[2];
    const float* targets   = (const float*)d_in[3];

    char* ws = (char*)d_ws;
    // layout: [0..8) loss_l, [8..16) loss_c, [64..576) num_pos[B],
    //         [1024..2048) posCE[B], [2048..18432) keys[B*16] u64,
    //         [18432..18944) candCnt[B] u32, [18944..19456) selBin[B],
    //         [19456..19968) selNeed[B], [19968..20992) selSumGt[B] f64,
    //         [32768..32768+4MB) hist[B*8192] u32,
    //         then cand[B*2048] f32 (1MB), then mined[B*P] f32
    double*             loss_l   = (double*)(ws + 0);
    double*             loss_c   = (double*)(ws + 8);
    int*                num_pos  = (int*)(ws + 64);
    double*             posCE    = (double*)(ws + 1024);
    unsigned long long* keys     = (unsigned long long*)(ws + 2048);
    unsigned*           candCnt  = (unsigned*)(ws + 18432);
    int*                selBin   = (int*)(ws + 18944);
    int*                selNeed  = (int*)(ws + 19456);
    double*             selSumGt = (double*)(ws + 19968);
    unsigned*           hist     = (unsigned*)(ws + 32768);
    float*              cand     = (float*)(ws + 32768 + (size_t)BB * HBINS * 4);
    float*              mined    = (float*)(ws + 32768 + (size_t)BB * HBINS * 4
                                               + (size_t)BB * CAND_MAX * 4);

    hipMemsetAsync(ws, 0, 32768 + (size_t)BB * HBINS * 4, stream);

    mb_phaseA<<<dim3(8, BB), 256, 0, stream>>>(priors, targets, keys);

    dim3 gridC((PP + 255) / 256, BB);
    mb_phaseC<<<gridC, 256, 0, stream>>>(loc_data, conf_data, priors, targets, keys,
                                         mined, num_pos, posCE, loss_l);

    mb_phaseD1<<<dim3(16, BB), 256, 0, stream>>>(mined, hist);

    mb_phaseD2a<<<BB, 256, 0, stream>>>(hist, num_pos, selBin, selNeed);

    mb_phaseD2b<<<dim3(16, BB), 256, 0, stream>>>(mined, selBin, candCnt, cand, selSumGt);

    mb_phaseD2c<<<BB, 256, 0, stream>>>(mined, selBin, selNeed, candCnt, cand,
                                        selSumGt, num_pos, posCE, loss_c);

    mb_phaseE<<<1, 128, 0, stream>>>(num_pos, loss_l, loss_c, (float*)d_out);
}

// Round 5
// 1016.946 us; speedup vs baseline: 1.1472x; 1.0284x over previous
//
#include <hip/hip_runtime.h>
#include <math.h>

#define BB 128
#define PP 34125
#define OO 16
#define CC 21
#define HBINS 4096     // bits>>19: sign(0)+exp(8)+3 mantissa -> all non-negative floats fit
#define HSHIFT 19
#define CAND_MAX 2048
#define VAR0f 0.1f
#define VAR1f 0.2f
#define THRESHf 0.35f

// ---------------- Phase A': zero workspace + per-block best-prior partials ----------------
// Each block writes its OWN slot keys2[(b*8+bx)*16+o] (no atomics, no pre-zero needed).
// Zeroing of hist/accumulators is fused here (replaces hipMemsetAsync dispatch).
__global__ __launch_bounds__(256) void mb_phaseA(const float* __restrict__ priors,
                                                 const float* __restrict__ targets,
                                                 unsigned long long* __restrict__ keys2,
                                                 unsigned* __restrict__ hist,
                                                 int* __restrict__ num_pos,
                                                 double* __restrict__ posCE,
                                                 double* __restrict__ loss_l,
                                                 double* __restrict__ loss_c,
                                                 unsigned* __restrict__ done) {
    int b = blockIdx.y, tid = threadIdx.x;
    int blk = b * 8 + blockIdx.x;   // 0..1023

    // ---- fused zeroing (disjoint slices; nothing zeroed here is read in this kernel) ----
    {
        unsigned* hz = hist + (size_t)blk * (BB * HBINS / 1024);   // 512 u32 per block
        hz[tid] = 0u;
        hz[tid + 256] = 0u;
    }
    if (blk == 0) {
        if (tid < BB) { num_pos[tid] = 0; posCE[tid] = 0.0; }
        if (tid == 0) { *loss_l = 0.0; *loss_c = 0.0; *done = 0u; }
    }

    __shared__ float tr[OO][4];
    __shared__ unsigned long long skeys[OO];
    if (tid < OO * 5) {
        int o = tid / 5, c = tid % 5;
        float v = targets[((size_t)b * OO + o) * 5 + c];
        if (c < 4) tr[o][c] = v;
    }
    if (tid < OO) skeys[tid] = 0ull;
    __syncthreads();

    unsigned long long best[OO];
#pragma unroll
    for (int o = 0; o < OO; o++) best[o] = 0ull;

    for (int p = blockIdx.x * 256 + tid; p < PP; p += gridDim.x * 256) {
        float4 pr = ((const float4*)priors)[p];
        float bx0 = pr.x - pr.z * 0.5f, by0 = pr.y - pr.w * 0.5f;
        float bx1 = pr.x + pr.z * 0.5f, by1 = pr.y + pr.w * 0.5f;
        float area_b = (bx1 - bx0) * (by1 - by0);
#pragma unroll
        for (int o = 0; o < OO; o++) {
            float iw = fminf(tr[o][2], bx1) - fmaxf(tr[o][0], bx0);
            float ih = fminf(tr[o][3], by1) - fmaxf(tr[o][1], by0);
            iw = fmaxf(iw, 0.f); ih = fmaxf(ih, 0.f);
            float inter = iw * ih;
            float area_a = (tr[o][2] - tr[o][0]) * (tr[o][3] - tr[o][1]);
            float iou = inter / (area_a + area_b - inter);
            unsigned long long key =
                ((unsigned long long)__float_as_uint(iou) << 32) |
                (unsigned long long)(0xFFFFFFFFu - (unsigned)p);
            if (key > best[o]) best[o] = key;
        }
    }
#pragma unroll
    for (int o = 0; o < OO; o++) {
        unsigned long long v = best[o];
        for (int off = 32; off > 0; off >>= 1) {
            unsigned long long other = __shfl_down(v, off, 64);
            if (other > v) v = other;
        }
        best[o] = v;
    }
    if ((tid & 63) == 0) {
#pragma unroll
        for (int o = 0; o < OO; o++) atomicMax(&skeys[o], best[o]);
    }
    __syncthreads();
    if (tid < OO) keys2[(size_t)blk * OO + tid] = skeys[tid];
}

// ---------------- Phase C: match + encode + smooth-L1 + CE + mined + LDS hist ----------------
__device__ __forceinline__ float sl1(float d) {
    float a = fabsf(d);
    return (a < 1.f) ? 0.5f * d * d : a - 0.5f;
}

__global__ __launch_bounds__(256) void mb_phaseC(const float* __restrict__ loc_data,
                                                 const float* __restrict__ conf_data,
                                                 const float* __restrict__ priors,
                                                 const float* __restrict__ targets,
                                                 const unsigned long long* __restrict__ keys2,
                                                 float* __restrict__ mined,
                                                 unsigned* __restrict__ hist,
                                                 int* __restrict__ num_pos,
                                                 double* __restrict__ posCE,
                                                 double* __restrict__ loss_l_acc) {
    int b = blockIdx.y, tid = threadIdx.x;
    int wave = tid >> 6, lane = tid & 63;
    int p = blockIdx.x * 256 + tid;

    __shared__ unsigned lh[HBINS];   // 16 KB block-private histogram
    __shared__ float tr[OO][4];
    __shared__ float lab[OO];
    __shared__ unsigned bps[OO];
    __shared__ float redf[8];
    __shared__ int redi[4];

    for (int i = tid; i < HBINS; i += 256) lh[i] = 0u;

    if (tid < OO * 5) {
        int o = tid / 5, c = tid % 5;
        float v = targets[((size_t)b * OO + o) * 5 + c];
        if (c < 4) tr[o][c] = v; else lab[o] = v;
    }
    if (tid < OO) {
        // reduce the 8 per-block partials (same result as the old atomicMax'd key)
        const unsigned long long* kb = keys2 + (size_t)b * 8 * OO;
        unsigned long long bk = 0ull;
#pragma unroll
        for (int j = 0; j < 8; j++) {
            unsigned long long v = kb[j * OO + tid];
            if (v > bk) bk = v;
        }
        bps[tid] = 0xFFFFFFFFu - (unsigned)(bk & 0xFFFFFFFFull);
    }
    // only barrier before the tail: publishes tr/lab/bps + lh zeroing, drains nothing heavy
    __syncthreads();

    float t_lossl = 0.f, t_posce = 0.f;
    int t_pos = 0;
    bool valid = (p < PP);

    // ---- issue this thread's 21 conf loads immediately (all-static reg indices) ----
    float creg[CC];
    if (valid) {
        const float* src = conf_data + ((size_t)b * PP + p) * CC;
#pragma unroll
        for (int c = 0; c < CC; c++) creg[c] = src[c];
    }

    if (valid) {
        // ---- IoU / match / encode / smooth-L1 while conf loads are in flight ----
        float4 pr = ((const float4*)priors)[p];
        float bx0 = pr.x - pr.z * 0.5f, by0 = pr.y - pr.w * 0.5f;
        float bx1 = pr.x + pr.z * 0.5f, by1 = pr.y + pr.w * 0.5f;
        float area_b = (bx1 - bx0) * (by1 - by0);
        float bto = -1.f;
        int bti = 0;
#pragma unroll
        for (int o = 0; o < OO; o++) {
            float iw = fminf(tr[o][2], bx1) - fmaxf(tr[o][0], bx0);
            float ih = fminf(tr[o][3], by1) - fmaxf(tr[o][1], by0);
            iw = fmaxf(iw, 0.f); ih = fmaxf(ih, 0.f);
            float inter = iw * ih;
            float area_a = (tr[o][2] - tr[o][0]) * (tr[o][3] - tr[o][1]);
            float iou = inter / (area_a + area_b - inter);
            if (iou > bto) { bto = iou; bti = o; }   // strict > : argmax first-index
        }
#pragma unroll
        for (int o = 0; o < OO; o++) {
            if (bps[o] == (unsigned)p) { bto = 2.0f; bti = o; }  // ascending o = last-wins
        }
        int conf_t = (bto < THRESHf) ? 0 : (int)lab[bti];
        bool pos = conf_t > 0;

        if (pos) {
            float mx0 = tr[bti][0], my0 = tr[bti][1], mx1 = tr[bti][2], my1 = tr[bti][3];
            float gcx = ((mx0 + mx1) * 0.5f - pr.x) / (VAR0f * pr.z);
            float gcy = ((my0 + my1) * 0.5f - pr.y) / (VAR0f * pr.w);
            float gw = __logf((mx1 - mx0) / pr.z) / VAR1f;
            float gh = __logf((my1 - my0) / pr.w) / VAR1f;
            float4 ld = ((const float4*)loc_data)[(size_t)b * PP + p];
            t_lossl = sl1(ld.x - gcx) + sl1(ld.y - gcy) + sl1(ld.z - gw) + sl1(ld.w - gh);
            t_pos = 1;
        }

        // ---- softmax CE from registers (same op order as verified version) ----
        float m = creg[0];
#pragma unroll
        for (int c = 1; c < CC; c++) m = fmaxf(m, creg[c]);
        float s = 0.f;
#pragma unroll
        for (int c = 0; c < CC; c++) s += __expf(creg[c] - m);
        float lse = m + __logf(s);
        float gat = creg[0];
#pragma unroll
        for (int c = 1; c < CC; c++) {
            if (c == conf_t) gat = creg[c];
        }
        float ce = lse - gat;
        if (pos) t_posce = ce;
        float mv = pos ? 0.f : ce;
        mined[(size_t)b * PP + p] = mv;
        atomicAdd(&lh[__float_as_uint(mv) >> HSHIFT], 1u);   // block-local, low contention
    }

    // wave shuffle reductions
    for (int off = 32; off > 0; off >>= 1) {
        t_lossl += __shfl_down(t_lossl, off, 64);
        t_posce += __shfl_down(t_posce, off, 64);
        t_pos   += __shfl_down(t_pos, off, 64);
    }
    if (lane == 0) { redf[wave] = t_lossl; redf[4 + wave] = t_posce; redi[wave] = t_pos; }
    __syncthreads();   // orders lh adds + redf/redi

    // sparse flush of block-private hist (fire-and-forget at kernel end)
    unsigned* gh = hist + (size_t)b * HBINS;
    for (int i = tid; i < HBINS; i += 256) {
        unsigned c = lh[i];
        if (c) atomicAdd(&gh[i], c);
    }

    if (tid == 0) {
        float ll = redf[0] + redf[1] + redf[2] + redf[3];
        float pc = redf[4] + redf[5] + redf[6] + redf[7];
        int np = redi[0] + redi[1] + redi[2] + redi[3];
        if (ll != 0.f) atomicAdd(loss_l_acc, (double)ll);
        if (pc != 0.f) atomicAdd(&posCE[b], (double)pc);
        if (np) atomicAdd(&num_pos[b], np);
    }
}

// ---------------- Phase D: fused select (bin-find + row scan + rank) + last-block finalize ----
__global__ __launch_bounds__(256) void mb_phaseD(const float* __restrict__ mined,
                                                 const unsigned* __restrict__ hist,
                                                 const int* __restrict__ num_pos,
                                                 const double* __restrict__ posCE,
                                                 double* __restrict__ loss_l,
                                                 double* __restrict__ loss_c,
                                                 unsigned* __restrict__ done,
                                                 float* __restrict__ out) {
    int b = blockIdx.x, tid = threadIdx.x;
    __shared__ double sd[256];
    __shared__ unsigned cs[256];
    __shared__ int sBin, sNeed;
    __shared__ float cand[CAND_MAX];   // 8 KB
    __shared__ unsigned ccnt;
    __shared__ unsigned rhist[256];
    __shared__ unsigned s_prefix;
    __shared__ int s_needed;
    __shared__ int si[256];
    __shared__ int sLast;

    int np = num_pos[b];
    int k = min(3 * np, PP - 1);
    const unsigned* h = hist + (size_t)b * HBINS;
    const float* row = mined + (size_t)b * PP;

    if (k <= 0) {
        if (tid == 0) atomicAdd(loss_c, posCE[b]);
    } else {
        const int CH = HBINS / 256;   // 16 bins per thread
        unsigned s = 0;
        for (int j = 0; j < CH; j++) s += h[tid * CH + j];
        cs[tid] = s;
        __syncthreads();
        if (tid == 0) {
            unsigned cum = 0;
            int t = 255;
            for (; t > 0; --t) {
                if (cum + cs[t] >= (unsigned)k) break;
                cum += cs[t];
            }
            int base = t * CH, bin = base;
            unsigned cum2 = cum;
            for (int j = CH - 1; j >= 1; --j) {
                unsigned c = h[base + j];
                if (cum2 + c >= (unsigned)k) { bin = base + j; break; }
                cum2 += c;
            }
            sBin = bin;
            sNeed = k - (int)cum2;   // 1..h[bin]
            ccnt = 0;
        }
        __syncthreads();
        int bin = sBin, need = sNeed;
        unsigned binCount = h[bin];   // exact (hist counts every mined value once)

        if (binCount <= CAND_MAX) {
            double sgt = 0.0;
            for (int p = tid; p < PP; p += 256) {
                float x = row[p];
                int bb2 = (int)(__float_as_uint(x) >> HSHIFT);
                if (bb2 > bin) sgt += (double)x;
                else if (bb2 == bin) { unsigned i = atomicAdd(&ccnt, 1u); cand[i] = x; }
            }
            sd[tid] = sgt;
            __syncthreads();
            for (int s2 = 128; s2 > 0; s2 >>= 1) {
                if (tid < s2) sd[tid] += sd[tid + s2];
                __syncthreads();
            }
            double sum_gt = sd[0];
            int n = (int)ccnt;
            __syncthreads();
            // exact rank-select: include candidate i iff stable-rank < need
            double st = 0.0;
            for (int i = tid; i < n; i += 256) {
                float v = cand[i];
                int r = 0;
                for (int j = 0; j < n; j++) {
                    float w = cand[j];
                    r += (w > v) || (w == v && j < i);
                }
                if (r < need) st += (double)v;
            }
            sd[tid] = st;
            __syncthreads();
            for (int s2 = 128; s2 > 0; s2 >>= 1) {
                if (tid < s2) sd[tid] += sd[tid + s2];
                __syncthreads();
            }
            if (tid == 0) atomicAdd(loss_c, posCE[b] + sum_gt + sd[0]);
        } else {
            // fallback: known-correct 4-pass byte radix select over full 32 bits
            unsigned prefix = 0;
            int needed = k;
            for (int pass = 0; pass < 4; pass++) {
                int shift = 24 - 8 * pass;
                rhist[tid] = 0;
                __syncthreads();
                unsigned hi_mask = (pass == 0) ? 0u : (0xFFFFFFFFu << (shift + 8));
                for (int p = tid; p < PP; p += 256) {
                    unsigned x = __float_as_uint(row[p]);
                    if ((x & hi_mask) == (prefix & hi_mask))
                        atomicAdd(&rhist[(x >> shift) & 0xFFu], 1u);
                }
                __syncthreads();
                if (tid == 0) {
                    unsigned cum = 0; int bsel = 0;
                    for (int j = 255; j >= 0; j--) {
                        if (cum + rhist[j] >= (unsigned)needed) { bsel = j; break; }
                        cum += rhist[j];
                    }
                    s_prefix = prefix | ((unsigned)bsel << shift);
                    s_needed = needed - (int)cum;
                }
                __syncthreads();
                prefix = s_prefix;
                needed = s_needed;
                __syncthreads();
            }
            float tv = __uint_as_float(prefix);
            double sum_gt = 0.0;
            for (int p = tid; p < PP; p += 256) {
                float x = row[p];
                if (__float_as_uint(x) > prefix) sum_gt += (double)x;
            }
            sd[tid] = sum_gt;
            __syncthreads();
            for (int s2 = 128; s2 > 0; s2 >>= 1) {
                if (tid < s2) sd[tid] += sd[tid + s2];
                __syncthreads();
            }
            if (tid == 0)
                atomicAdd(loss_c, posCE[b] + sd[0] + (double)needed * (double)tv);
        }
    }

    // ---- ticket: last finishing block computes the final output (replaces phase E) ----
    __syncthreads();
    if (tid == 0) {
        __threadfence();                       // make this block's loss_c add visible
        unsigned t = atomicAdd(done, 1u);
        sLast = (t == (unsigned)(BB - 1)) ? 1 : 0;
    }
    __syncthreads();
    if (sLast) {
        si[tid] = (tid < BB) ? num_pos[tid] : 0;
        __syncthreads();
        for (int s2 = 128; s2 > 0; s2 >>= 1) {
            if (tid < s2) si[tid] += si[tid + s2];
            __syncthreads();
        }
        if (tid == 0) {
            __threadfence();
            double lc = atomicAdd(loss_c, 0.0);   // device-scope read (XCD-safe)
            double ll = atomicAdd(loss_l, 0.0);
            int n = si[0];
            double N = (n > 0) ? (double)n : (double)BB;
            out[0] = (float)(ll / N);
            out[1] = (float)(lc / N);
        }
    }
}

extern "C" void kernel_launch(void* const* d_in, const int* in_sizes, int n_in,
                              void* d_out, int out_size, void* d_ws, size_t ws_size,
                              hipStream_t stream) {
    const float* loc_data  = (const float*)d_in[0];
    const float* conf_data = (const float*)d_in[1];
    const float* priors    = (const float*)d_in[2];
    const float* targets   = (const float*)d_in[3];

    char* ws = (char*)d_ws;
    // layout: [0..8) loss_l, [8..16) loss_c, [16..20) done,
    //         [64..576) num_pos[B], [1024..2048) posCE[B],
    //         [2048..18432) keys2[B*8*16] u64,
    //         [32768..32768+2MB) hist[B*4096] u32, then mined[B*P] f32
    double*             loss_l  = (double*)(ws + 0);
    double*             loss_c  = (double*)(ws + 8);
    unsigned*           done    = (unsigned*)(ws + 16);
    int*                num_pos = (int*)(ws + 64);
    double*             posCE   = (double*)(ws + 1024);
    unsigned long long* keys2   = (unsigned long long*)(ws + 2048);
    unsigned*           hist    = (unsigned*)(ws + 32768);
    float*              mined   = (float*)(ws + 32768 + (size_t)BB * HBINS * 4);

    mb_phaseA<<<dim3(8, BB), 256, 0, stream>>>(priors, targets, keys2, hist,
                                               num_pos, posCE, loss_l, loss_c, done);

    dim3 gridC((PP + 255) / 256, BB);
    mb_phaseC<<<gridC, 256, 0, stream>>>(loc_data, conf_data, priors, targets, keys2,
                                         mined, hist, num_pos, posCE, loss_l);

    mb_phaseD<<<BB, 256, 0, stream>>>(mined, hist, num_pos, posCE,
                                      loss_l, loss_c, done, (float*)d_out);
}